// Round 8
// baseline (370.224 us; speedup 1.0000x reference)
//
#include <hip/hip_runtime.h>
#include <hip/hip_cooperative_groups.h>

// NonLocalBlock3D v7: cooperative mega-kernel (LDS trimmed to 64KB, Yt
// aliased onto KtA) with CHECKED launch + fallback to the proven R5
// 4-kernel chain if the cooperative launch is rejected.
// MFMA v_mfma_f32_32x32x16_bf16; layouts (m74/m101):
//   A-frag: lane holds A[l&31][8*(l>>5)+u]
//   B-frag: lane holds B[8*(l>>5)+u][l&31]
//   C/D:    col = l&31, row = (r&3) + 8*(r>>2) + 4*(l>>5)

typedef __bf16 bf16x8 __attribute__((ext_vector_type(8)));
typedef __bf16 bf16x4 __attribute__((ext_vector_type(4)));
typedef float f32x16 __attribute__((ext_vector_type(16)));

#define DEV __device__ __forceinline__

constexpr int NROW = 8192;   // N
constexpr int CDIM = 256;    // C
constexpr int DI   = 128;    // INTER
constexpr int KVS  = 16;     // kv splits for flash
constexpr int NIT  = NROW / KVS / 64;   // 8 tiles of 64 kv per sweep
constexpr float MFIX = 32.0f;           // fixed softmax max (base-2 units)
constexpr float LOG2E = 1.44269504f;

DEV int crow(int r, int h) { return (r & 3) + 8 * (r >> 2) + 4 * h; }

DEV f32x16 mfma(bf16x8 a, bf16x8 b, f32x16 c) {
    return __builtin_amdgcn_mfma_f32_32x32x16_bf16(a, b, c, 0, 0, 0);
}

DEV unsigned pack2(float a, float b) {
    union { __bf16 h[2]; unsigned u; } t;
    t.h[0] = (__bf16)a; t.h[1] = (__bf16)b;
    return t.u;
}

// async 16B global -> LDS (dest = wave-uniform base + lane*16)
DEV void dma16(const void* g, void* l) {
    __builtin_amdgcn_global_load_lds(
        (const __attribute__((address_space(1))) unsigned*)g,
        (__attribute__((address_space(3))) unsigned*)l, 16, 0, 0);
}

// ===========================================================================
// Cooperative mega-kernel
// ===========================================================================
__global__ __launch_bounds__(256, 2) void fused(
    const float* __restrict__ x,
    const float* __restrict__ g_w,  const float* __restrict__ g_b,
    const float* __restrict__ th_w, const float* __restrict__ th_b,
    const float* __restrict__ ph_w, const float* __restrict__ ph_b,
    const float* __restrict__ W_w,  const float* __restrict__ W_b,
    float* __restrict__ out,
    __bf16* __restrict__ qws, __bf16* __restrict__ kws, __bf16* __restrict__ vTws,
    __bf16* __restrict__ thT, __bf16* __restrict__ phT, __bf16* __restrict__ gTw,
    __bf16* __restrict__ WwT, float* __restrict__ mll, __bf16* __restrict__ yac)
{
    __shared__ __align__(16) __bf16 KtA[2][64 * 128];  // flash K; P3 reuses as Yt
    __shared__ __align__(16) __bf16 VtA[2][64 * 128];  // flash V

    auto grid = cooperative_groups::this_grid();
    const int bid = blockIdx.x, tid = threadIdx.x;
    const int wv = tid >> 6, lane = tid & 63, l31 = lane & 31, h = lane >> 5;

    // ================= P0: weight transpose/cast =================
    {
        int o = bid * 256 + tid;            // [0, 131072)
        int m = o >> 15, o15 = o & 32767;
        if (m < 3) {
            const float* in = m == 0 ? th_w : m == 1 ? ph_w : g_w;  // [256k][128n]
            __bf16* ow      = m == 0 ? thT  : m == 1 ? phT  : gTw;  // [128n][256k]
            int n = o15 >> 8, kk = o15 & 255;
            ow[o15] = (__bf16)in[kk * DI + n];
        } else {
            int c = o15 >> 7, kk = o15 & 127;                        // WwT [256c][128k]
            WwT[o15] = (__bf16)W_w[kk * CDIM + c];
        }
    }
    grid.sync();

    // ================= P1: projections (384 tasks) =================
    if (bid < 384) {
        const int which = bid >> 7, bx = bid & 127;
        const __bf16* wt  = which == 0 ? thT : which == 1 ? phT : gTw;
        const float* bias = which == 0 ? th_b : which == 1 ? ph_b : g_b;
        const int rsel = wv & 1, csel = wv >> 1;

        if (which < 2) {
            __bf16* o = which == 0 ? qws : kws;
            const float osc = which == 0 ? LOG2E : 1.0f;
            const int row0 = bx * 64 + rsel * 32;
            f32x16 acc[2] = {};
#pragma unroll
            for (int kk = 0; kk < 16; ++kk) {
                const float4* xp = (const float4*)(x + (size_t)(row0 + l31) * CDIM + kk * 16 + h * 8);
                float4 a0 = xp[0], a1 = xp[1];
                bf16x8 af;
                af[0] = (__bf16)a0.x; af[1] = (__bf16)a0.y; af[2] = (__bf16)a0.z; af[3] = (__bf16)a0.w;
                af[4] = (__bf16)a1.x; af[5] = (__bf16)a1.y; af[6] = (__bf16)a1.z; af[7] = (__bf16)a1.w;
#pragma unroll
                for (int jn = 0; jn < 2; ++jn) {
                    int col0 = csel * 64 + jn * 32;
                    bf16x8 bfr = *(const bf16x8*)(wt + (size_t)(col0 + l31) * CDIM + kk * 16 + h * 8);
                    acc[jn] = mfma(af, bfr, acc[jn]);
                }
            }
#pragma unroll
            for (int jn = 0; jn < 2; ++jn) {
                int col = csel * 64 + jn * 32 + l31;
                float bv = bias[col];
#pragma unroll
                for (int r = 0; r < 16; ++r)
                    o[(size_t)(row0 + crow(r, h)) * DI + col] = (__bf16)((acc[jn][r] + bv) * osc);
            }
        } else {
            const int xr0 = bx * 64 + rsel * 32;
            f32x16 acc[2] = {};
#pragma unroll
            for (int kk = 0; kk < 16; ++kk) {
                const float4* xp = (const float4*)(x + (size_t)(xr0 + l31) * CDIM + kk * 16 + h * 8);
                float4 b0 = xp[0], b1 = xp[1];
                bf16x8 bf;
                bf[0] = (__bf16)b0.x; bf[1] = (__bf16)b0.y; bf[2] = (__bf16)b0.z; bf[3] = (__bf16)b0.w;
                bf[4] = (__bf16)b1.x; bf[5] = (__bf16)b1.y; bf[6] = (__bf16)b1.z; bf[7] = (__bf16)b1.w;
#pragma unroll
                for (int jn = 0; jn < 2; ++jn) {
                    int i0 = csel * 64 + jn * 32;
                    bf16x8 afr = *(const bf16x8*)(wt + (size_t)(i0 + l31) * CDIM + kk * 16 + h * 8);
                    acc[jn] = mfma(afr, bf, acc[jn]);
                }
            }
#pragma unroll
            for (int jn = 0; jn < 2; ++jn) {
                int i0 = csel * 64 + jn * 32;
#pragma unroll
                for (int r = 0; r < 16; ++r) {
                    int i = i0 + crow(r, h);
                    vTws[(size_t)i * NROW + xr0 + l31] = (__bf16)(acc[jn][r] + bias[i]);
                }
            }
        }
    }
    grid.sync();

    // ================= P2: flash, 2 sweeps per block =================
    int koff[16], voff[16];
#pragma unroll
    for (int kk = 0; kk < 8; ++kk)
#pragma unroll
        for (int jm = 0; jm < 2; ++jm) {
            int kv = jm * 32 + l31;
            koff[kk * 2 + jm] = (kv * 128 + kk * 16 + h * 8) ^ ((kv & 15) << 3);
        }
#pragma unroll
    for (int jd = 0; jd < 4; ++jd)
#pragma unroll
        for (int ks = 0; ks < 4; ++ks) {
            int d = jd * 32 + l31, rw = d >> 1;
            voff[jd * 4 + ks] = (rw * 128 + (d & 1) * 64 + ks * 16 + h * 8) ^ ((rw & 15) << 3);
        }

    for (int t = bid; t < 1024; t += 512) {
        const int sp = t & 15, qt = t >> 4;   // sp constant across both sweeps
        const int q0 = qt * 128 + wv * 32;
        const int kvbase = sp * (NROW / KVS);

        bf16x8 qf[8];
#pragma unroll
        for (int kk = 0; kk < 8; ++kk)
            qf[kk] = *(const bf16x8*)(qws + (size_t)(q0 + l31) * DI + kk * 16 + h * 8);

        const __bf16* kSrc[4];
        const __bf16* vSrc[4];
#pragma unroll
        for (int rr = 0; rr < 4; ++rr) {
            int cix = rr * 256 + wv * 64 + lane;
            int r = cix >> 4, c = (cix & 15) ^ (r & 15);
            kSrc[rr] = kws + (size_t)(kvbase + r) * DI + c * 8;
            int d = r * 2 + (c >> 3), kv8 = (c & 7) * 8;
            vSrc[rr] = vTws + (size_t)d * NROW + kvbase + kv8;
        }

#define STAGE(KT, VT)                                                         \
    {                                                                         \
        _Pragma("unroll")                                                     \
        for (int rr = 0; rr < 4; ++rr) {                                      \
            dma16(kSrc[rr], (char*)(KT) + rr * 4096 + wv * 1024);             \
            kSrc[rr] += 64 * DI;                                              \
        }                                                                     \
        _Pragma("unroll")                                                     \
        for (int rr = 0; rr < 4; ++rr) {                                      \
            dma16(vSrc[rr], (char*)(VT) + rr * 4096 + wv * 1024);             \
            vSrc[rr] += 64;                                                   \
        }                                                                     \
    }

        f32x16 yacc[4] = {};
        float l = 0.f;

        STAGE(KtA[0], VtA[0]);
        __syncthreads();

        for (int it = 0; it < NIT; ++it) {
            const int cur = it & 1;
            if (it < NIT - 1) STAGE(KtA[cur ^ 1], VtA[cur ^ 1]);

            const __bf16* Kt = KtA[cur];
            const __bf16* Vt = VtA[cur];

            f32x16 sacc[2] = {};
            __builtin_amdgcn_s_setprio(1);
#pragma unroll
            for (int kk = 0; kk < 8; ++kk)
#pragma unroll
                for (int jm = 0; jm < 2; ++jm) {
                    bf16x8 kf = *(const bf16x8*)(&Kt[koff[kk * 2 + jm]]);
                    sacc[jm] = mfma(kf, qf[kk], sacc[jm]);
                }
            __builtin_amdgcn_s_setprio(0);

            float ts = 0.f;
#pragma unroll
            for (int jm = 0; jm < 2; ++jm)
#pragma unroll
                for (int r = 0; r < 16; ++r) {
                    float p = exp2f(sacc[jm][r] - MFIX);
                    sacc[jm][r] = p;
                    ts += p;
                }
            ts += __shfl_xor(ts, 32);
            l += ts;

            bf16x8 pf[4];
#pragma unroll
            for (int ks = 0; ks < 4; ++ks) {
                const int jm = ks >> 1, r0 = 8 * (ks & 1);
                unsigned a0 = pack2(sacc[jm][r0],     sacc[jm][r0 + 1]);
                unsigned a1 = pack2(sacc[jm][r0 + 2], sacc[jm][r0 + 3]);
                unsigned b0 = pack2(sacc[jm][r0 + 4], sacc[jm][r0 + 5]);
                unsigned b1 = pack2(sacc[jm][r0 + 6], sacc[jm][r0 + 7]);
                unsigned snd0 = h ? a0 : b0, snd1 = h ? a1 : b1;
                unsigned loc0 = h ? b0 : a0, loc1 = h ? b1 : a1;
                unsigned rcv0 = (unsigned)__shfl_xor((int)snd0, 32);
                unsigned rcv1 = (unsigned)__shfl_xor((int)snd1, 32);
                union { unsigned w[4]; bf16x8 v; } pu;
                pu.w[0] = h ? rcv0 : loc0;
                pu.w[1] = h ? rcv1 : loc1;
                pu.w[2] = h ? loc0 : rcv0;
                pu.w[3] = h ? loc1 : rcv1;
                pf[ks] = pu.v;
            }

            __builtin_amdgcn_s_setprio(1);
#pragma unroll
            for (int jd = 0; jd < 4; ++jd)
#pragma unroll
                for (int ks = 0; ks < 4; ++ks) {
                    bf16x8 vf = *(const bf16x8*)(&Vt[voff[jd * 4 + ks]]);
                    yacc[jd] = mfma(vf, pf[ks], yacc[jd]);
                }
            __builtin_amdgcn_s_setprio(0);

            __syncthreads();
        }
#undef STAGE

        const size_t qrow = (size_t)sp * NROW + q0 + l31;
#pragma unroll
        for (int jd = 0; jd < 4; ++jd)
#pragma unroll
            for (int rq = 0; rq < 4; ++rq) {
                bf16x4 tb;
#pragma unroll
                for (int i = 0; i < 4; ++i) tb[i] = (__bf16)yacc[jd][rq * 4 + i];
                *(bf16x4*)(yac + qrow * DI + jd * 32 + rq * 8 + h * 4) = tb;
            }
        if (h == 0) mll[sp * NROW + q0 + l31] = l;
    }
    grid.sync();
    __syncthreads();   // insurance: all P2 LDS use done before Yt reuse

    // ================= P3: merge + final projection (512 tasks) ==========
    {
        __bf16* Yt = (__bf16*)KtA;          // reuse 8KB of flash K LDS
        const int rt = bid >> 1, ch = bid & 1;
        const int row0 = rt * 32;

        {
            const int qq = tid >> 3, ds = tid & 7;   // 32 q x 8 d-slices of 16
            float L = 0.f;
#pragma unroll
            for (int s = 0; s < KVS; ++s) L += mll[s * NROW + row0 + qq];
            const float rL = 1.f / L;
            float fa[16] = {};
#pragma unroll
            for (int s = 0; s < KVS; ++s) {
                const __bf16* p = yac + ((size_t)s * NROW + row0 + qq) * DI + ds * 16;
                bf16x8 v0 = *(const bf16x8*)p;
                bf16x8 v1 = *(const bf16x8*)(p + 8);
#pragma unroll
                for (int i = 0; i < 8; ++i) { fa[i] += (float)v0[i]; fa[8 + i] += (float)v1[i]; }
            }
            bf16x8 o0, o1;
#pragma unroll
            for (int i = 0; i < 8; ++i) { o0[i] = (__bf16)(fa[i] * rL); o1[i] = (__bf16)(fa[8 + i] * rL); }
            int base = qq * 128 + ds * 16;
            *(bf16x8*)(&Yt[base ^ ((qq & 7) << 3)])       = o0;
            *(bf16x8*)(&Yt[(base + 8) ^ ((qq & 7) << 3)]) = o1;
        }
        __syncthreads();

        bf16x8 af[8];
#pragma unroll
        for (int kk = 0; kk < 8; ++kk)
            af[kk] = *(const bf16x8*)(&Yt[(l31 * 128 + kk * 16 + h * 8) ^ ((l31 & 7) << 3)]);

        const int col0 = ch * 128 + wv * 32;
        f32x16 acc = {};
#pragma unroll
        for (int kk = 0; kk < 8; ++kk) {
            bf16x8 bfr = *(const bf16x8*)(WwT + (size_t)(col0 + l31) * DI + kk * 16 + h * 8);
            acc = mfma(af[kk], bfr, acc);
        }

        const int col = col0 + l31;
        const float bv = W_b[col];
#pragma unroll
        for (int r = 0; r < 16; ++r) {
            int row = row0 + crow(r, h);
            out[(size_t)row * CDIM + col] = acc[r] + bv + x[(size_t)row * CDIM + col];
        }
    }
}

// ===========================================================================
// Fallback chain (R5, measured 157.7us, passed)
// ===========================================================================
__global__ void prep_wT(const float* __restrict__ thw, const float* __restrict__ phw,
                        const float* __restrict__ gw,  const float* __restrict__ Ww,
                        __bf16* __restrict__ thT, __bf16* __restrict__ phT,
                        __bf16* __restrict__ gT,  __bf16* __restrict__ WwT)
{
    const int m = blockIdx.y;
    const int o = blockIdx.x * 256 + threadIdx.x;
    if (m < 3) {
        const float* in = m == 0 ? thw : m == 1 ? phw : gw;
        __bf16* out = m == 0 ? thT : m == 1 ? phT : gT;
        int n = o >> 8, kk = o & 255;
        out[o] = (__bf16)in[kk * DI + n];
    } else {
        int c = o >> 7, kk = o & 127;
        WwT[o] = (__bf16)Ww[kk * CDIM + c];
    }
}

__global__ __launch_bounds__(256) void proj3(
    const float* __restrict__ x,
    const __bf16* __restrict__ thT, const float* __restrict__ thb,
    const __bf16* __restrict__ phT, const float* __restrict__ phb,
    const __bf16* __restrict__ gT,  const float* __restrict__ gb,
    __bf16* __restrict__ qo, __bf16* __restrict__ ko, __bf16* __restrict__ vT)
{
    const int which = blockIdx.y;
    const __bf16* wt  = which == 0 ? thT : which == 1 ? phT : gT;
    const float* bias = which == 0 ? thb : which == 1 ? phb : gb;
    const int tid = threadIdx.x;
    const int wv = tid >> 6, lane = tid & 63, l31 = lane & 31, h = lane >> 5;
    const int rsel = wv & 1, csel = wv >> 1;

    if (which < 2) {
        __bf16* o = which == 0 ? qo : ko;
        const float osc = which == 0 ? LOG2E : 1.0f;
        const int row0 = blockIdx.x * 64 + rsel * 32;
        f32x16 acc[2] = {};
#pragma unroll
        for (int kk = 0; kk < 16; ++kk) {
            const float4* xp = (const float4*)(x + (size_t)(row0 + l31) * CDIM + kk * 16 + h * 8);
            float4 a0 = xp[0], a1 = xp[1];
            bf16x8 af;
            af[0] = (__bf16)a0.x; af[1] = (__bf16)a0.y; af[2] = (__bf16)a0.z; af[3] = (__bf16)a0.w;
            af[4] = (__bf16)a1.x; af[5] = (__bf16)a1.y; af[6] = (__bf16)a1.z; af[7] = (__bf16)a1.w;
#pragma unroll
            for (int jn = 0; jn < 2; ++jn) {
                int col0 = csel * 64 + jn * 32;
                bf16x8 bfr = *(const bf16x8*)(wt + (size_t)(col0 + l31) * CDIM + kk * 16 + h * 8);
                acc[jn] = mfma(af, bfr, acc[jn]);
            }
        }
#pragma unroll
        for (int jn = 0; jn < 2; ++jn) {
            int col = csel * 64 + jn * 32 + l31;
            float bv = bias[col];
#pragma unroll
            for (int r = 0; r < 16; ++r)
                o[(size_t)(row0 + crow(r, h)) * DI + col] = (__bf16)((acc[jn][r] + bv) * osc);
        }
    } else {
        const int xr0 = blockIdx.x * 64 + rsel * 32;
        f32x16 acc[2] = {};
#pragma unroll
        for (int kk = 0; kk < 16; ++kk) {
            const float4* xp = (const float4*)(x + (size_t)(xr0 + l31) * CDIM + kk * 16 + h * 8);
            float4 b0 = xp[0], b1 = xp[1];
            bf16x8 bf;
            bf[0] = (__bf16)b0.x; bf[1] = (__bf16)b0.y; bf[2] = (__bf16)b0.z; bf[3] = (__bf16)b0.w;
            bf[4] = (__bf16)b1.x; bf[5] = (__bf16)b1.y; bf[6] = (__bf16)b1.z; bf[7] = (__bf16)b1.w;
#pragma unroll
            for (int jn = 0; jn < 2; ++jn) {
                int i0 = csel * 64 + jn * 32;
                bf16x8 afr = *(const bf16x8*)(wt + (size_t)(i0 + l31) * CDIM + kk * 16 + h * 8);
                acc[jn] = mfma(afr, bf, acc[jn]);
            }
        }
#pragma unroll
        for (int jn = 0; jn < 2; ++jn) {
            int i0 = csel * 64 + jn * 32;
#pragma unroll
            for (int r = 0; r < 16; ++r) {
                int i = i0 + crow(r, h);
                vT[(size_t)i * NROW + xr0 + l31] = (__bf16)(acc[jn][r] + bias[i]);
            }
        }
    }
}

__global__ __launch_bounds__(256, 2) void flash(
    const __bf16* __restrict__ q, const __bf16* __restrict__ k,
    const __bf16* __restrict__ vT, __bf16* __restrict__ yac,
    float* __restrict__ mll)
{
    __shared__ __align__(16) __bf16 KtA[2][64 * 128];
    __shared__ __align__(16) __bf16 VtA[2][64 * 128];

    const int tid = threadIdx.x;
    const int wv = tid >> 6, lane = tid & 63, l31 = lane & 31, h = lane >> 5;
    const int bid = blockIdx.x;
    const int sp = bid & 15, qt = bid >> 4;
    const int q0 = qt * 128 + wv * 32;
    const int kvbase = sp * (NROW / KVS);

    bf16x8 qf[8];
#pragma unroll
    for (int kk = 0; kk < 8; ++kk)
        qf[kk] = *(const bf16x8*)(q + (size_t)(q0 + l31) * DI + kk * 16 + h * 8);

    f32x16 yacc[4] = {};
    float l = 0.f;

    const __bf16* kSrc[4];
    const __bf16* vSrc[4];
#pragma unroll
    for (int rr = 0; rr < 4; ++rr) {
        int cix = rr * 256 + wv * 64 + lane;
        int r = cix >> 4, c = (cix & 15) ^ (r & 15);
        kSrc[rr] = k + (size_t)(kvbase + r) * DI + c * 8;
        int d = r * 2 + (c >> 3), kv8 = (c & 7) * 8;
        vSrc[rr] = vT + (size_t)d * NROW + kvbase + kv8;
    }

#define STAGE(KT, VT)                                                         \
    {                                                                         \
        _Pragma("unroll")                                                     \
        for (int rr = 0; rr < 4; ++rr) {                                      \
            dma16(kSrc[rr], (char*)(KT) + rr * 4096 + wv * 1024);             \
            kSrc[rr] += 64 * DI;                                              \
        }                                                                     \
        _Pragma("unroll")                                                     \
        for (int rr = 0; rr < 4; ++rr) {                                      \
            dma16(vSrc[rr], (char*)(VT) + rr * 4096 + wv * 1024);             \
            vSrc[rr] += 64;                                                   \
        }                                                                     \
    }

    STAGE(KtA[0], VtA[0]);
    __syncthreads();

    for (int it = 0; it < NIT; ++it) {
        const int cur = it & 1;
        if (it < NIT - 1) STAGE(KtA[cur ^ 1], VtA[cur ^ 1]);

        const __bf16* Kt = KtA[cur];
        const __bf16* Vt = VtA[cur];

        f32x16 sacc[2] = {};
        __builtin_amdgcn_s_setprio(1);
#pragma unroll
        for (int kk = 0; kk < 8; ++kk)
#pragma unroll
            for (int jm = 0; jm < 2; ++jm) {
                int kv = jm * 32 + l31;
                bf16x8 kf = *(const bf16x8*)(&Kt[(kv * 128 + kk * 16 + h * 8) ^ ((kv & 15) << 3)]);
                sacc[jm] = mfma(kf, qf[kk], sacc[jm]);
            }
        __builtin_amdgcn_s_setprio(0);

        float ts = 0.f;
#pragma unroll
        for (int jm = 0; jm < 2; ++jm)
#pragma unroll
            for (int r = 0; r < 16; ++r) {
                float p = exp2f(sacc[jm][r] - MFIX);
                sacc[jm][r] = p;
                ts += p;
            }
        ts += __shfl_xor(ts, 32);
        l += ts;

        bf16x8 pf[4];
#pragma unroll
        for (int ks = 0; ks < 4; ++ks) {
            const int jm = ks >> 1, r0 = 8 * (ks & 1);
            unsigned a0 = pack2(sacc[jm][r0],     sacc[jm][r0 + 1]);
            unsigned a1 = pack2(sacc[jm][r0 + 2], sacc[jm][r0 + 3]);
            unsigned b0 = pack2(sacc[jm][r0 + 4], sacc[jm][r0 + 5]);
            unsigned b1 = pack2(sacc[jm][r0 + 6], sacc[jm][r0 + 7]);
            unsigned snd0 = h ? a0 : b0, snd1 = h ? a1 : b1;
            unsigned loc0 = h ? b0 : a0, loc1 = h ? b1 : a1;
            unsigned rcv0 = (unsigned)__shfl_xor((int)snd0, 32);
            unsigned rcv1 = (unsigned)__shfl_xor((int)snd1, 32);
            union { unsigned w[4]; bf16x8 v; } pu;
            pu.w[0] = h ? rcv0 : loc0;
            pu.w[1] = h ? rcv1 : loc1;
            pu.w[2] = h ? loc0 : rcv0;
            pu.w[3] = h ? loc1 : rcv1;
            pf[ks] = pu.v;
        }

        __builtin_amdgcn_s_setprio(1);
#pragma unroll
        for (int jd = 0; jd < 4; ++jd) {
            int d = jd * 32 + l31, rw = d >> 1;
#pragma unroll
            for (int ks = 0; ks < 4; ++ks) {
                int co = (d & 1) * 64 + ks * 16 + h * 8;
                bf16x8 vf = *(const bf16x8*)(&Vt[(rw * 128 + co) ^ ((rw & 15) << 3)]);
                yacc[jd] = mfma(vf, pf[ks], yacc[jd]);
            }
        }
        __builtin_amdgcn_s_setprio(0);

        __syncthreads();
    }
#undef STAGE

    const size_t qrow = (size_t)sp * NROW + q0 + l31;
#pragma unroll
    for (int jd = 0; jd < 4; ++jd)
#pragma unroll
        for (int rq = 0; rq < 4; ++rq) {
            bf16x4 tb;
#pragma unroll
            for (int i = 0; i < 4; ++i) tb[i] = (__bf16)yacc[jd][rq * 4 + i];
            *(bf16x4*)(yac + qrow * DI + jd * 32 + rq * 8 + h * 4) = tb;
        }
    if (h == 0) mll[sp * NROW + q0 + l31] = l;
}

__global__ __launch_bounds__(512) void merge_final(
    const __bf16* __restrict__ yac, const float* __restrict__ mll,
    const __bf16* __restrict__ WwT, const float* __restrict__ bias,
    const float* __restrict__ x, float* __restrict__ out)
{
    __shared__ __align__(16) __bf16 Yt[32 * 128];

    const int tid = threadIdx.x;
    const int row0 = blockIdx.x * 32;

    {
        const int qq = tid >> 4, ds = tid & 15;
        float L = 0.f;
#pragma unroll
        for (int s = 0; s < KVS; ++s) L += mll[s * NROW + row0 + qq];
        const float rL = 1.f / L;
        float fa[8] = {};
#pragma unroll
        for (int s = 0; s < KVS; ++s) {
            bf16x8 v = *(const bf16x8*)(yac + ((size_t)s * NROW + row0 + qq) * DI + ds * 8);
#pragma unroll
            for (int i = 0; i < 8; ++i) fa[i] += (float)v[i];
        }
        bf16x8 o;
#pragma unroll
        for (int i = 0; i < 8; ++i) o[i] = (__bf16)(fa[i] * rL);
        *(bf16x8*)(&Yt[(qq * 128 + ds * 8) ^ ((qq & 7) << 3)]) = o;
    }
    __syncthreads();

    const int wv = tid >> 6, lane = tid & 63, l31 = lane & 31, h = lane >> 5;
    bf16x8 af[8];
#pragma unroll
    for (int kk = 0; kk < 8; ++kk)
        af[kk] = *(const bf16x8*)(&Yt[(l31 * 128 + kk * 16 + h * 8) ^ ((l31 & 7) << 3)]);

    f32x16 acc = {};
#pragma unroll
    for (int kk = 0; kk < 8; ++kk) {
        bf16x8 bfr = *(const bf16x8*)(WwT + (size_t)(wv * 32 + l31) * DI + kk * 16 + h * 8);
        acc = mfma(af[kk], bfr, acc);
    }

    const int col = wv * 32 + l31;
    const float bv = bias[col];
#pragma unroll
    for (int r = 0; r < 16; ++r) {
        int row = row0 + crow(r, h);
        out[(size_t)row * CDIM + col] = acc[r] + bv + x[(size_t)row * CDIM + col];
    }
}

// ---------------------------------------------------------------------------
extern "C" void kernel_launch(void* const* d_in, const int* in_sizes, int n_in,
                              void* d_out, int out_size, void* d_ws, size_t ws_size,
                              hipStream_t stream)
{
    const float* x    = (const float*)d_in[0];
    const float* g_w  = (const float*)d_in[1];
    const float* g_b  = (const float*)d_in[2];
    const float* th_w = (const float*)d_in[3];
    const float* th_b = (const float*)d_in[4];
    const float* ph_w = (const float*)d_in[5];
    const float* ph_b = (const float*)d_in[6];
    const float* W_w  = (const float*)d_in[7];
    const float* W_b  = (const float*)d_in[8];
    float* out = (float*)d_out;

    char* ws = (char*)d_ws;
    __bf16* qws  = (__bf16*)(ws);                                 // 2 MB theta (pre-scaled)
    __bf16* kws  = (__bf16*)(ws + (2ull << 20));                  // 2 MB phi
    __bf16* vTws = (__bf16*)(ws + (4ull << 20));                  // 2 MB g^T
    __bf16* thT  = (__bf16*)(ws + (6ull << 20));                  // 64 KB
    __bf16* phT  = (__bf16*)(ws + (6ull << 20) + (64ull << 10));  // 64 KB
    __bf16* gTw  = (__bf16*)(ws + (6ull << 20) + (128ull << 10)); // 64 KB
    __bf16* WwT  = (__bf16*)(ws + (6ull << 20) + (192ull << 10)); // 64 KB
    float*  mll  = (float*)(ws + (6ull << 20) + (256ull << 10));  // 512 KB
    __bf16* yac  = (__bf16*)(ws + (7ull << 20));                  // 32 MB bf16 partials

    void* args[] = {
        (void*)&x, (void*)&g_w, (void*)&g_b, (void*)&th_w, (void*)&th_b,
        (void*)&ph_w, (void*)&ph_b, (void*)&W_w, (void*)&W_b, (void*)&out,
        (void*)&qws, (void*)&kws, (void*)&vTws, (void*)&thT, (void*)&phT,
        (void*)&gTw, (void*)&WwT, (void*)&mll, (void*)&yac
    };
    hipError_t e = hipLaunchCooperativeKernel((const void*)fused, dim3(512),
                                              dim3(256), args, 0, stream);
    if (e != hipSuccess) {
        // proven R5 path (157.7us)
        prep_wT<<<dim3(128, 4), 256, 0, stream>>>(th_w, ph_w, g_w, W_w,
                                                  thT, phT, gTw, WwT);
        proj3<<<dim3(128, 3), 256, 0, stream>>>(x, thT, th_b, phT, ph_b,
                                                gTw, g_b, qws, kws, vTws);
        flash<<<1024, 256, 0, stream>>>(qws, kws, vTws, yac, mll);
        merge_final<<<256, 512, 0, stream>>>(yac, mll, WwT, W_b, x, out);
    }
}

// Round 10
// 198.393 us; speedup vs baseline: 1.8661x; 1.8661x over previous
//
#include <hip/hip_runtime.h>

// NonLocalBlock3D v8: 4-kernel chain (mega-kernel abandoned, R8 evidence).
//   prep_wT -> proj3 (32-row tiles, grid (256,3)) ->
//   flash (KVBLK=32, LDS 32KB dbuf -> 4 blocks/CU, DMA staging w/
//          pre-swizzled src, fixed-max exp2 softmax, T12 reg P-exchange,
//          KVS=16 XCD-pinned, 1 barrier/iter) -> merge_final.
// MFMA v_mfma_f32_32x32x16_bf16; layouts (m74/m101):
//   A-frag: lane holds A[l&31][8*(l>>5)+u]
//   B-frag: lane holds B[8*(l>>5)+u][l&31]
//   C/D:    col = l&31, row = (r&3) + 8*(r>>2) + 4*(l>>5)

typedef __bf16 bf16x8 __attribute__((ext_vector_type(8)));
typedef __bf16 bf16x4 __attribute__((ext_vector_type(4)));
typedef float f32x16 __attribute__((ext_vector_type(16)));

#define DEV __device__ __forceinline__

constexpr int NROW = 8192;   // N
constexpr int CDIM = 256;    // C
constexpr int DI   = 128;    // INTER
constexpr int KVS  = 16;     // kv splits for flash
constexpr int KVB  = 32;     // kv tile per iteration
constexpr int NIT  = NROW / KVS / KVB;  // 16 iters per block
constexpr float MFIX = 32.0f;           // fixed softmax max (base-2 units)
constexpr float LOG2E = 1.44269504f;

DEV int crow(int r, int h) { return (r & 3) + 8 * (r >> 2) + 4 * h; }

DEV f32x16 mfma(bf16x8 a, bf16x8 b, f32x16 c) {
    return __builtin_amdgcn_mfma_f32_32x32x16_bf16(a, b, c, 0, 0, 0);
}

DEV unsigned pack2(float a, float b) {
    union { __bf16 h[2]; unsigned u; } t;
    t.h[0] = (__bf16)a; t.h[1] = (__bf16)b;
    return t.u;
}

// async 16B global -> LDS (dest = wave-uniform base + lane*16)
DEV void dma16(const void* g, void* l) {
    __builtin_amdgcn_global_load_lds(
        (const __attribute__((address_space(1))) unsigned*)g,
        (__attribute__((address_space(3))) unsigned*)l, 16, 0, 0);
}

// ---------------------------------------------------------------------------
// prep_wT: transpose the three [256][128] fp32 weights -> [128][256] bf16,
// and W_w [128][256] -> [256][128] bf16. grid (128,4), block 256.
// ---------------------------------------------------------------------------
__global__ void prep_wT(const float* __restrict__ thw, const float* __restrict__ phw,
                        const float* __restrict__ gw,  const float* __restrict__ Ww,
                        __bf16* __restrict__ thT, __bf16* __restrict__ phT,
                        __bf16* __restrict__ gT,  __bf16* __restrict__ WwT)
{
    const int m = blockIdx.y;
    const int o = blockIdx.x * 256 + threadIdx.x;    // [0, 32768)
    if (m < 3) {
        const float* in = m == 0 ? thw : m == 1 ? phw : gw;   // [256 k][128 n]
        __bf16* out = m == 0 ? thT : m == 1 ? phT : gT;       // [128 n][256 k]
        int n = o >> 8, kk = o & 255;
        out[o] = (__bf16)in[kk * DI + n];
    } else {
        int c = o >> 7, kk = o & 127;                 // WwT [256 c][128 k]
        WwT[o] = (__bf16)Ww[kk * CDIM + c];
    }
}

// ---------------------------------------------------------------------------
// proj3: blockIdx.y in {0:theta, 1:phi} -> out[row][n] row-major bf16;
//        blockIdx.y == 2 (g)            -> outT[n][row] transposed bf16.
// 32-row tiles, 1 wave = 1 col(or i)-quarter. grid (256,3), 3 blocks/CU.
// theta output pre-scaled by log2e for exp2 softmax.
// ---------------------------------------------------------------------------
__global__ __launch_bounds__(256, 4) void proj3(
    const float* __restrict__ x,
    const __bf16* __restrict__ thT, const float* __restrict__ thb,
    const __bf16* __restrict__ phT, const float* __restrict__ phb,
    const __bf16* __restrict__ gT,  const float* __restrict__ gb,
    __bf16* __restrict__ qo, __bf16* __restrict__ ko, __bf16* __restrict__ vT)
{
    const int which = blockIdx.y;
    const __bf16* wt  = which == 0 ? thT : which == 1 ? phT : gT;
    const float* bias = which == 0 ? thb : which == 1 ? phb : gb;

    const int tid = threadIdx.x;
    const int wv = tid >> 6, lane = tid & 63, l31 = lane & 31, h = lane >> 5;

    if (which < 2) {
        __bf16* o = which == 0 ? qo : ko;
        const float osc = which == 0 ? LOG2E : 1.0f;
        const int row0 = blockIdx.x * 32;
        const int col0 = wv * 32;
        f32x16 acc = {};
#pragma unroll
        for (int kk = 0; kk < 16; ++kk) {
            const float4* xp = (const float4*)(x + (size_t)(row0 + l31) * CDIM + kk * 16 + h * 8);
            float4 a0 = xp[0], a1 = xp[1];
            bf16x8 af;
            af[0] = (__bf16)a0.x; af[1] = (__bf16)a0.y; af[2] = (__bf16)a0.z; af[3] = (__bf16)a0.w;
            af[4] = (__bf16)a1.x; af[5] = (__bf16)a1.y; af[6] = (__bf16)a1.z; af[7] = (__bf16)a1.w;
            bf16x8 bfr = *(const bf16x8*)(wt + (size_t)(col0 + l31) * CDIM + kk * 16 + h * 8);
            acc = mfma(af, bfr, acc);
        }
        const int col = col0 + l31;
        const float bv = bias[col];
#pragma unroll
        for (int r = 0; r < 16; ++r)
            o[(size_t)(row0 + crow(r, h)) * DI + col] = (__bf16)((acc[r] + bv) * osc);
    } else {
        const int xr0 = blockIdx.x * 32;
        const int i0 = wv * 32;
        f32x16 acc = {};
#pragma unroll
        for (int kk = 0; kk < 16; ++kk) {
            const float4* xp = (const float4*)(x + (size_t)(xr0 + l31) * CDIM + kk * 16 + h * 8);
            float4 b0 = xp[0], b1 = xp[1];
            bf16x8 bf;
            bf[0] = (__bf16)b0.x; bf[1] = (__bf16)b0.y; bf[2] = (__bf16)b0.z; bf[3] = (__bf16)b0.w;
            bf[4] = (__bf16)b1.x; bf[5] = (__bf16)b1.y; bf[6] = (__bf16)b1.z; bf[7] = (__bf16)b1.w;
            bf16x8 afr = *(const bf16x8*)(wt + (size_t)(i0 + l31) * CDIM + kk * 16 + h * 8);
            acc = mfma(afr, bf, acc);
        }
#pragma unroll
        for (int r = 0; r < 16; ++r) {
            int i = i0 + crow(r, h);
            vT[(size_t)i * NROW + xr0 + l31] = (__bf16)(acc[r] + bias[i]);
        }
    }
}

// ---------------------------------------------------------------------------
// flash v8: KVBLK=32 -> LDS 32KB dbuf -> 4 blocks/CU (16 waves/CU).
// DMA staging with pre-swizzled per-lane SOURCE (chunk XOR involution).
// Fixed-max exp2 softmax; T12 in-register P exchange; 1 barrier/iter.
// grid 1024 (64 qt x 16 sp), block 256 (4 waves x 32 q).
// K tile [32 kv][128 d]; V tile packed [d>>2][(d&3)*32+kv] (32 x 128).
// ---------------------------------------------------------------------------
__global__ __launch_bounds__(256, 4) void flash(
    const __bf16* __restrict__ q, const __bf16* __restrict__ k,
    const __bf16* __restrict__ vT, __bf16* __restrict__ yac,
    float* __restrict__ mll)
{
    __shared__ __align__(16) __bf16 KtA[2][KVB * 128];  // 8KB each
    __shared__ __align__(16) __bf16 VtA[2][KVB * 128];  // 8KB each

    const int tid = threadIdx.x;
    const int wv = tid >> 6, lane = tid & 63, l31 = lane & 31, h = lane >> 5;
    const int bid = blockIdx.x;
    const int sp = bid & 15, qt = bid >> 4;
    const int q0 = qt * 128 + wv * 32;
    const int kvbase = sp * (NROW / KVS);

    bf16x8 qf[8];
#pragma unroll
    for (int kk = 0; kk < 8; ++kk)
        qf[kk] = *(const bf16x8*)(q + (size_t)(q0 + l31) * DI + kk * 16 + h * 8);

    // precomputed swizzled LDS read offsets
    int koff[8], voff[8];
#pragma unroll
    for (int kk = 0; kk < 8; ++kk)
        koff[kk] = (l31 * 128 + kk * 16 + h * 8) ^ ((l31 & 15) << 3);
#pragma unroll
    for (int jd = 0; jd < 4; ++jd)
#pragma unroll
        for (int ks = 0; ks < 2; ++ks) {
            int d = jd * 32 + l31, rw = d >> 2;
            voff[jd * 2 + ks] = (rw * 128 + (d & 3) * 32 + ks * 16 + h * 8) ^ ((rw & 15) << 3);
        }

    // hoisted per-lane staging source pointers (chunk XOR pre-applied)
    const __bf16* kSrc[2];
    const __bf16* vSrc[2];
#pragma unroll
    for (int j = 0; j < 2; ++j) {
        int cix = j * 256 + wv * 64 + lane;          // [0, 512)
        int r = cix >> 4, c = (cix & 15) ^ (r & 15);
        kSrc[j] = k + (size_t)(kvbase + r) * DI + c * 8;
        int d = r * 4 + (c >> 2), kv8 = (c & 3) * 8;
        vSrc[j] = vT + (size_t)d * NROW + kvbase + kv8;
    }

#define STAGE(KT, VT)                                                         \
    {                                                                         \
        _Pragma("unroll")                                                     \
        for (int j = 0; j < 2; ++j) {                                         \
            dma16(kSrc[j], (char*)(KT) + j * 4096 + wv * 1024);               \
            kSrc[j] += KVB * DI;                                              \
        }                                                                     \
        _Pragma("unroll")                                                     \
        for (int j = 0; j < 2; ++j) {                                         \
            dma16(vSrc[j], (char*)(VT) + j * 4096 + wv * 1024);               \
            vSrc[j] += KVB;                                                   \
        }                                                                     \
    }

    f32x16 yacc[4] = {};
    float l = 0.f;

    STAGE(KtA[0], VtA[0]);
    __syncthreads();

    for (int it = 0; it < NIT; ++it) {
        const int cur = it & 1;
        if (it < NIT - 1) STAGE(KtA[cur ^ 1], VtA[cur ^ 1]);

        const __bf16* Kt = KtA[cur];
        const __bf16* Vt = VtA[cur];

        // S^T = K . Q^T  (32 kv x 32 q per wave)
        f32x16 sacc = {};
        __builtin_amdgcn_s_setprio(1);
#pragma unroll
        for (int kk = 0; kk < 8; ++kk) {
            bf16x8 kf = *(const bf16x8*)(&Kt[koff[kk]]);
            sacc = mfma(kf, qf[kk], sacc);
        }
        __builtin_amdgcn_s_setprio(0);

        // fixed-max softmax: P = 2^(s - 32), s already in base-2 units
        float ts = 0.f;
#pragma unroll
        for (int r = 0; r < 16; ++r) {
            float p = exp2f(sacc[r] - MFIX);
            sacc[r] = p;
            ts += p;
        }
        ts += __shfl_xor(ts, 32);
        l += ts;

        // T12: P -> bf16 B-fragments via pack + shfl_xor(32)
        bf16x8 pf[2];
#pragma unroll
        for (int ks = 0; ks < 2; ++ks) {
            const int r0 = 8 * ks;
            unsigned a0 = pack2(sacc[r0],     sacc[r0 + 1]);
            unsigned a1 = pack2(sacc[r0 + 2], sacc[r0 + 3]);
            unsigned b0 = pack2(sacc[r0 + 4], sacc[r0 + 5]);
            unsigned b1 = pack2(sacc[r0 + 6], sacc[r0 + 7]);
            unsigned snd0 = h ? a0 : b0, snd1 = h ? a1 : b1;
            unsigned loc0 = h ? b0 : a0, loc1 = h ? b1 : a1;
            unsigned rcv0 = (unsigned)__shfl_xor((int)snd0, 32);
            unsigned rcv1 = (unsigned)__shfl_xor((int)snd1, 32);
            union { unsigned w[4]; bf16x8 v; } pu;
            pu.w[0] = h ? rcv0 : loc0;
            pu.w[1] = h ? rcv1 : loc1;
            pu.w[2] = h ? loc0 : rcv0;
            pu.w[3] = h ? loc1 : rcv1;
            pf[ks] = pu.v;
        }

        // y^T += V^T . P^T
        __builtin_amdgcn_s_setprio(1);
#pragma unroll
        for (int jd = 0; jd < 4; ++jd)
#pragma unroll
            for (int ks = 0; ks < 2; ++ks) {
                bf16x8 vf = *(const bf16x8*)(&Vt[voff[jd * 2 + ks]]);
                yacc[jd] = mfma(vf, pf[ks], yacc[jd]);
            }
        __builtin_amdgcn_s_setprio(0);

        __syncthreads();   // drains DMA vmcnt + LDS reads; buffers swap
    }
#undef STAGE

    // store partials bf16, [s][q][d] layout (d = jd*32 + rq*8 + h*4 + i)
    const size_t qrow = (size_t)sp * NROW + q0 + l31;
#pragma unroll
    for (int jd = 0; jd < 4; ++jd)
#pragma unroll
        for (int rq = 0; rq < 4; ++rq) {
            bf16x4 tb;
#pragma unroll
            for (int i = 0; i < 4; ++i) tb[i] = (__bf16)yacc[jd][rq * 4 + i];
            *(bf16x4*)(yac + qrow * DI + jd * 32 + rq * 8 + h * 4) = tb;
        }
    if (h == 0) mll[sp * NROW + q0 + l31] = l;
}

// ---------------------------------------------------------------------------
// merge_final: y[q][d] = (sum_s yac[s][q][d]) / (sum_s l_s[q]); then
// out[row][c] = y[row][:] @ W[:,c] + Wb[c] + x[row][c]  (fp32 out).
// grid 256 x 32 rows, block 512 (8 waves, 32 cols each). LDS 8KB swizzled.
// ---------------------------------------------------------------------------
__global__ __launch_bounds__(512) void merge_final(
    const __bf16* __restrict__ yac, const float* __restrict__ mll,
    const __bf16* __restrict__ WwT, const float* __restrict__ bias,
    const float* __restrict__ x, float* __restrict__ out)
{
    __shared__ __align__(16) __bf16 Yt[32 * 128];   // [q][d], swz ^((q&7)<<3)

    const int tid = threadIdx.x;
    const int row0 = blockIdx.x * 32;

    // phase 1: merge partials -> normalized y tile in LDS
    {
        const int qq = tid >> 4, ds = tid & 15;     // 32 q x 16 d-slices
        float L = 0.f;
#pragma unroll
        for (int s = 0; s < KVS; ++s) L += mll[s * NROW + row0 + qq];
        const float rL = 1.f / L;
        float fa[8] = {};
#pragma unroll
        for (int s = 0; s < KVS; ++s) {
            bf16x8 v = *(const bf16x8*)(yac + ((size_t)s * NROW + row0 + qq) * DI + ds * 8);
#pragma unroll
            for (int i = 0; i < 8; ++i) fa[i] += (float)v[i];
        }
        bf16x8 o;
#pragma unroll
        for (int i = 0; i < 8; ++i) o[i] = (__bf16)(fa[i] * rL);
        *(bf16x8*)(&Yt[(qq * 128 + ds * 8) ^ ((qq & 7) << 3)]) = o;
    }
    __syncthreads();

    // phase 2: W projection + bias + residual
    const int wv = tid >> 6, lane = tid & 63, l31 = lane & 31, h = lane >> 5;
    bf16x8 af[8];
#pragma unroll
    for (int kk = 0; kk < 8; ++kk)
        af[kk] = *(const bf16x8*)(&Yt[(l31 * 128 + kk * 16 + h * 8) ^ ((l31 & 7) << 3)]);

    f32x16 acc = {};
#pragma unroll
    for (int kk = 0; kk < 8; ++kk) {
        bf16x8 bfr = *(const bf16x8*)(WwT + (size_t)(wv * 32 + l31) * DI + kk * 16 + h * 8);
        acc = mfma(af[kk], bfr, acc);
    }

    const int col = wv * 32 + l31;
    const float bv = bias[col];
#pragma unroll
    for (int r = 0; r < 16; ++r) {
        int row = row0 + crow(r, h);
        out[(size_t)row * CDIM + col] = acc[r] + bv + x[(size_t)row * CDIM + col];
    }
}

// ---------------------------------------------------------------------------
extern "C" void kernel_launch(void* const* d_in, const int* in_sizes, int n_in,
                              void* d_out, int out_size, void* d_ws, size_t ws_size,
                              hipStream_t stream)
{
    const float* x    = (const float*)d_in[0];
    const float* g_w  = (const float*)d_in[1];
    const float* g_b  = (const float*)d_in[2];
    const float* th_w = (const float*)d_in[3];
    const float* th_b = (const float*)d_in[4];
    const float* ph_w = (const float*)d_in[5];
    const float* ph_b = (const float*)d_in[6];
    const float* W_w  = (const float*)d_in[7];
    const float* W_b  = (const float*)d_in[8];
    float* out = (float*)d_out;

    char* ws = (char*)d_ws;
    __bf16* qws  = (__bf16*)(ws);                                 // 2 MB theta (pre-scaled)
    __bf16* kws  = (__bf16*)(ws + (2ull << 20));                  // 2 MB phi
    __bf16* vTws = (__bf16*)(ws + (4ull << 20));                  // 2 MB g^T
    __bf16* thT  = (__bf16*)(ws + (6ull << 20));                  // 64 KB
    __bf16* phT  = (__bf16*)(ws + (6ull << 20) + (64ull << 10));  // 64 KB
    __bf16* gTw  = (__bf16*)(ws + (6ull << 20) + (128ull << 10)); // 64 KB
    __bf16* WwT  = (__bf16*)(ws + (6ull << 20) + (192ull << 10)); // 64 KB
    float*  mll  = (float*)(ws + (6ull << 20) + (256ull << 10));  // 512 KB
    __bf16* yac  = (__bf16*)(ws + (7ull << 20));                  // 32 MB bf16 partials

    prep_wT<<<dim3(128, 4), 256, 0, stream>>>(th_w, ph_w, g_w, W_w,
                                              thT, phT, gTw, WwT);
    proj3<<<dim3(256, 3), 256, 0, stream>>>(x, thT, th_b, phT, ph_b,
                                            gTw, g_b, qws, kws, vTws);
    flash<<<1024, 256, 0, stream>>>(qws, kws, vTws, yac, mll);
    merge_final<<<256, 512, 0, stream>>>(yac, mll, WwT, W_b, x, out);
}

// Round 11
// 153.677 us; speedup vs baseline: 2.4091x; 1.2910x over previous
//
#include <hip/hip_runtime.h>

// NonLocalBlock3D v9: best-measured composition.
//   prep_wT -> proj3 (32-row tiles, grid (256,3), theta pre-scaled log2e) ->
//   flash (R3 structure: KVS=8, KVB=64, reg-stage + ds_write-late, 64KB dbuf,
//          1 barrier/iter, XCD pinning; + fixed-max exp2 softmax + T12 reg
//          P-exchange + bf16 [s][q][d] partials) ->
//   merge_final (KVS=8, grid 512x256).
// MFMA v_mfma_f32_32x32x16_bf16; layouts (m74/m101):
//   A-frag: lane holds A[l&31][8*(l>>5)+u]
//   B-frag: lane holds B[8*(l>>5)+u][l&31]
//   C/D:    col = l&31, row = (r&3) + 8*(r>>2) + 4*(l>>5)

typedef __bf16 bf16x8 __attribute__((ext_vector_type(8)));
typedef __bf16 bf16x4 __attribute__((ext_vector_type(4)));
typedef float f32x16 __attribute__((ext_vector_type(16)));

#define DEV __device__ __forceinline__

constexpr int NROW = 8192;   // N
constexpr int CDIM = 256;    // C
constexpr int DI   = 128;    // INTER
constexpr int KVS  = 8;      // kv splits for flash
constexpr int NIT  = NROW / KVS / 64;   // 16 tiles of 64 kv per split
constexpr float MFIX = 32.0f;           // fixed softmax max (base-2 units)
constexpr float LOG2E = 1.44269504f;

DEV int crow(int r, int h) { return (r & 3) + 8 * (r >> 2) + 4 * h; }

DEV f32x16 mfma(bf16x8 a, bf16x8 b, f32x16 c) {
    return __builtin_amdgcn_mfma_f32_32x32x16_bf16(a, b, c, 0, 0, 0);
}

DEV unsigned pack2(float a, float b) {
    union { __bf16 h[2]; unsigned u; } t;
    t.h[0] = (__bf16)a; t.h[1] = (__bf16)b;
    return t.u;
}

// ---------------------------------------------------------------------------
// prep_wT: transpose the three [256][128] fp32 weights -> [128][256] bf16,
// and W_w [128][256] -> [256][128] bf16. grid (128,4), block 256.
// ---------------------------------------------------------------------------
__global__ void prep_wT(const float* __restrict__ thw, const float* __restrict__ phw,
                        const float* __restrict__ gw,  const float* __restrict__ Ww,
                        __bf16* __restrict__ thT, __bf16* __restrict__ phT,
                        __bf16* __restrict__ gT,  __bf16* __restrict__ WwT)
{
    const int m = blockIdx.y;
    const int o = blockIdx.x * 256 + threadIdx.x;    // [0, 32768)
    if (m < 3) {
        const float* in = m == 0 ? thw : m == 1 ? phw : gw;   // [256 k][128 n]
        __bf16* out = m == 0 ? thT : m == 1 ? phT : gT;       // [128 n][256 k]
        int n = o >> 8, kk = o & 255;
        out[o] = (__bf16)in[kk * DI + n];
    } else {
        int c = o >> 7, kk = o & 127;                 // WwT [256 c][128 k]
        WwT[o] = (__bf16)Ww[kk * CDIM + c];
    }
}

// ---------------------------------------------------------------------------
// proj3: blockIdx.y in {0:theta, 1:phi} -> out[row][n] row-major bf16;
//        blockIdx.y == 2 (g)            -> outT[n][row] transposed bf16.
// 32-row tiles, 1 wave = 1 col(or i)-quarter. grid (256,3).
// theta output pre-scaled by log2e for exp2 softmax.
// ---------------------------------------------------------------------------
__global__ __launch_bounds__(256, 4) void proj3(
    const float* __restrict__ x,
    const __bf16* __restrict__ thT, const float* __restrict__ thb,
    const __bf16* __restrict__ phT, const float* __restrict__ phb,
    const __bf16* __restrict__ gT,  const float* __restrict__ gb,
    __bf16* __restrict__ qo, __bf16* __restrict__ ko, __bf16* __restrict__ vT)
{
    const int which = blockIdx.y;
    const __bf16* wt  = which == 0 ? thT : which == 1 ? phT : gT;
    const float* bias = which == 0 ? thb : which == 1 ? phb : gb;

    const int tid = threadIdx.x;
    const int wv = tid >> 6, lane = tid & 63, l31 = lane & 31, h = lane >> 5;

    if (which < 2) {
        __bf16* o = which == 0 ? qo : ko;
        const float osc = which == 0 ? LOG2E : 1.0f;
        const int row0 = blockIdx.x * 32;
        const int col0 = wv * 32;
        f32x16 acc = {};
#pragma unroll
        for (int kk = 0; kk < 16; ++kk) {
            const float4* xp = (const float4*)(x + (size_t)(row0 + l31) * CDIM + kk * 16 + h * 8);
            float4 a0 = xp[0], a1 = xp[1];
            bf16x8 af;
            af[0] = (__bf16)a0.x; af[1] = (__bf16)a0.y; af[2] = (__bf16)a0.z; af[3] = (__bf16)a0.w;
            af[4] = (__bf16)a1.x; af[5] = (__bf16)a1.y; af[6] = (__bf16)a1.z; af[7] = (__bf16)a1.w;
            bf16x8 bfr = *(const bf16x8*)(wt + (size_t)(col0 + l31) * CDIM + kk * 16 + h * 8);
            acc = mfma(af, bfr, acc);
        }
        const int col = col0 + l31;
        const float bv = bias[col];
#pragma unroll
        for (int r = 0; r < 16; ++r)
            o[(size_t)(row0 + crow(r, h)) * DI + col] = (__bf16)((acc[r] + bv) * osc);
    } else {
        const int xr0 = blockIdx.x * 32;
        const int i0 = wv * 32;
        f32x16 acc = {};
#pragma unroll
        for (int kk = 0; kk < 16; ++kk) {
            const float4* xp = (const float4*)(x + (size_t)(xr0 + l31) * CDIM + kk * 16 + h * 8);
            float4 b0 = xp[0], b1 = xp[1];
            bf16x8 bf;
            bf[0] = (__bf16)b0.x; bf[1] = (__bf16)b0.y; bf[2] = (__bf16)b0.z; bf[3] = (__bf16)b0.w;
            bf[4] = (__bf16)b1.x; bf[5] = (__bf16)b1.y; bf[6] = (__bf16)b1.z; bf[7] = (__bf16)b1.w;
            bf16x8 afr = *(const bf16x8*)(wt + (size_t)(i0 + l31) * CDIM + kk * 16 + h * 8);
            acc = mfma(afr, bf, acc);
        }
#pragma unroll
        for (int r = 0; r < 16; ++r) {
            int i = i0 + crow(r, h);
            vT[(size_t)i * NROW + xr0 + l31] = (__bf16)(acc[r] + bias[i]);
        }
    }
}

// ---------------------------------------------------------------------------
// flash v9: R3's measured-best structure (58.7us): KVS=8, sp=bid&7 XCD-pinned,
// KVB=64, reg-stage (global->reg early, ds_write late), 64KB LDS dbuf,
// ONE barrier/iter. Plus: fixed-max exp2 softmax (theta pre-scaled log2e),
// T12 in-register P exchange, bf16 [s][q][d] partials (16MB).
// grid 512 (64 qt x 8 sp), block 256 (4 waves x 32 q).
// ---------------------------------------------------------------------------
__global__ __launch_bounds__(256, 2) void flash(
    const __bf16* __restrict__ q, const __bf16* __restrict__ k,
    const __bf16* __restrict__ vT, __bf16* __restrict__ yac,
    float* __restrict__ mll)
{
    __shared__ __align__(16) __bf16 KtA[2][64 * 128];  // [kv][d], swz ^((kv&15)<<3)
    __shared__ __align__(16) __bf16 VtA[2][64 * 128];  // [d>>1][(d&1)*64+kv], swz ^((rw&15)<<3)

    const int tid = threadIdx.x;
    const int wv = tid >> 6, lane = tid & 63, l31 = lane & 31, h = lane >> 5;
    const int bid = blockIdx.x;
    const int sp = bid & 7, qt = bid >> 3;     // XCD = bid%8 -> split pinned per XCD
    const int q0 = qt * 128 + wv * 32;
    const size_t kvbase = (size_t)sp * (NROW / KVS);

    bf16x8 qf[8];
#pragma unroll
    for (int kk = 0; kk < 8; ++kk)
        qf[kk] = *(const bf16x8*)(q + (size_t)(q0 + l31) * DI + kk * 16 + h * 8);

    f32x16 yacc[4] = {};
    float l = 0.f;

    bf16x8 kr[4], vr[4];
    // prologue: stage tile 0 into buf 0
    {
#pragma unroll
        for (int j = 0; j < 4; ++j) {
            int cid = j * 256 + tid, r = cid >> 4, dc = (cid & 15) * 8;
            kr[j] = *(const bf16x8*)(k + (kvbase + r) * DI + dc);
        }
#pragma unroll
        for (int j = 0; j < 4; ++j) {
            int cid = j * 256 + tid, d = cid >> 3, kvc = (cid & 7) * 8;
            vr[j] = *(const bf16x8*)(vT + (size_t)d * NROW + kvbase + kvc);
        }
#pragma unroll
        for (int j = 0; j < 4; ++j) {
            int cid = j * 256 + tid, r = cid >> 4, dc = (cid & 15) * 8;
            *(bf16x8*)(&KtA[0][(r * 128 + dc) ^ ((r & 15) << 3)]) = kr[j];
        }
#pragma unroll
        for (int j = 0; j < 4; ++j) {
            int cid = j * 256 + tid, d = cid >> 3, kvc = (cid & 7) * 8;
            int rw = d >> 1, co = (d & 1) * 64 + kvc;
            *(bf16x8*)(&VtA[0][(rw * 128 + co) ^ ((rw & 15) << 3)]) = vr[j];
        }
    }
    __syncthreads();

    for (int it = 0; it < NIT; ++it) {
        const __bf16* Kt = KtA[it & 1];
        const __bf16* Vt = VtA[it & 1];

        // T14: issue next tile's global loads before compute
        if (it < NIT - 1) {
            const size_t kvb_n = kvbase + (size_t)(it + 1) * 64;
#pragma unroll
            for (int j = 0; j < 4; ++j) {
                int cid = j * 256 + tid, r = cid >> 4, dc = (cid & 15) * 8;
                kr[j] = *(const bf16x8*)(k + (kvb_n + r) * DI + dc);
            }
#pragma unroll
            for (int j = 0; j < 4; ++j) {
                int cid = j * 256 + tid, d = cid >> 3, kvc = (cid & 7) * 8;
                vr[j] = *(const bf16x8*)(vT + (size_t)d * NROW + kvb_n + kvc);
            }
        }

        // S^T = K . Q^T
        f32x16 sacc[2] = {};
        __builtin_amdgcn_s_setprio(1);
#pragma unroll
        for (int kk = 0; kk < 8; ++kk) {
#pragma unroll
            for (int jm = 0; jm < 2; ++jm) {
                int kv = jm * 32 + l31;
                bf16x8 kf = *(const bf16x8*)(&Kt[(kv * 128 + kk * 16 + h * 8) ^ ((kv & 15) << 3)]);
                sacc[jm] = mfma(kf, qf[kk], sacc[jm]);
            }
        }
        __builtin_amdgcn_s_setprio(0);

        // fixed-max softmax: P = 2^(s - 32), s already in base-2 units
        float ts = 0.f;
#pragma unroll
        for (int jm = 0; jm < 2; ++jm)
#pragma unroll
            for (int r = 0; r < 16; ++r) {
                float p = exp2f(sacc[jm][r] - MFIX);
                sacc[jm][r] = p;
                ts += p;
            }
        ts += __shfl_xor(ts, 32);
        l += ts;

        // T12: P -> bf16 fragments via pack + shfl_xor(32) (no LDS round-trip)
        bf16x8 pf[4];
#pragma unroll
        for (int ks = 0; ks < 4; ++ks) {
            const int jm = ks >> 1, r0 = 8 * (ks & 1);
            unsigned a0 = pack2(sacc[jm][r0],     sacc[jm][r0 + 1]);
            unsigned a1 = pack2(sacc[jm][r0 + 2], sacc[jm][r0 + 3]);
            unsigned b0 = pack2(sacc[jm][r0 + 4], sacc[jm][r0 + 5]);
            unsigned b1 = pack2(sacc[jm][r0 + 6], sacc[jm][r0 + 7]);
            unsigned snd0 = h ? a0 : b0, snd1 = h ? a1 : b1;
            unsigned loc0 = h ? b0 : a0, loc1 = h ? b1 : a1;
            unsigned rcv0 = (unsigned)__shfl_xor((int)snd0, 32);
            unsigned rcv1 = (unsigned)__shfl_xor((int)snd1, 32);
            union { unsigned w[4]; bf16x8 v; } pu;
            pu.w[0] = h ? rcv0 : loc0;
            pu.w[1] = h ? rcv1 : loc1;
            pu.w[2] = h ? loc0 : rcv0;
            pu.w[3] = h ? loc1 : rcv1;
            pf[ks] = pu.v;
        }

        // y^T += V^T . P^T
        __builtin_amdgcn_s_setprio(1);
#pragma unroll
        for (int jd = 0; jd < 4; ++jd) {
            int d = jd * 32 + l31, rw = d >> 1;
#pragma unroll
            for (int ks = 0; ks < 4; ++ks) {
                int co = (d & 1) * 64 + ks * 16 + h * 8;
                bf16x8 vf = *(const bf16x8*)(&Vt[(rw * 128 + co) ^ ((rw & 15) << 3)]);
                yacc[jd] = mfma(vf, pf[ks], yacc[jd]);
            }
        }
        __builtin_amdgcn_s_setprio(0);

        // write next tile into the other buffer (safe: single barrier/iter)
        if (it < NIT - 1) {
            __bf16* Ktn = KtA[(it + 1) & 1];
            __bf16* Vtn = VtA[(it + 1) & 1];
#pragma unroll
            for (int j = 0; j < 4; ++j) {
                int cid = j * 256 + tid, r = cid >> 4, dc = (cid & 15) * 8;
                *(bf16x8*)(&Ktn[(r * 128 + dc) ^ ((r & 15) << 3)]) = kr[j];
            }
#pragma unroll
            for (int j = 0; j < 4; ++j) {
                int cid = j * 256 + tid, d = cid >> 3, kvc = (cid & 7) * 8;
                int rw = d >> 1, co = (d & 1) * 64 + kvc;
                *(bf16x8*)(&Vtn[(rw * 128 + co) ^ ((rw & 15) << 3)]) = vr[j];
            }
        }
        __syncthreads();
    }

    // store partials bf16, [s][q][d] layout
    const size_t qrow = (size_t)sp * NROW + q0 + l31;
#pragma unroll
    for (int jd = 0; jd < 4; ++jd)
#pragma unroll
        for (int rq = 0; rq < 4; ++rq) {
            bf16x4 tb;
#pragma unroll
            for (int i = 0; i < 4; ++i) tb[i] = (__bf16)yacc[jd][rq * 4 + i];
            *(bf16x4*)(yac + qrow * DI + jd * 32 + rq * 8 + h * 4) = tb;
        }
    if (h == 0) mll[sp * NROW + q0 + l31] = l;
}

// ---------------------------------------------------------------------------
// merge_final: y[q][d] = (sum_s yac[s][q][d]) / (sum_s l_s[q]); then
// out[row][c] = y[row][:] @ W[:,c] + Wb[c] + x[row][c]  (fp32 out).
// grid 512 (256 row-tiles x 2 col-halves), block 256 (4 waves). LDS 8KB.
// ---------------------------------------------------------------------------
__global__ __launch_bounds__(256, 2) void merge_final(
    const __bf16* __restrict__ yac, const float* __restrict__ mll,
    const __bf16* __restrict__ WwT, const float* __restrict__ bias,
    const float* __restrict__ x, float* __restrict__ out)
{
    __shared__ __align__(16) __bf16 Yt[32 * 128];   // [q][d], swz ^((q&7)<<3)

    const int tid = threadIdx.x;
    const int rt = blockIdx.x >> 1, ch = blockIdx.x & 1;
    const int row0 = rt * 32;

    // phase 1: merge partials -> normalized y tile [32 q][128 d] in LDS
    {
        const int qq = tid >> 3, ds = tid & 7;   // 32 q x 8 d-slices of 16
        float L = 0.f;
#pragma unroll
        for (int s = 0; s < KVS; ++s) L += mll[s * NROW + row0 + qq];
        const float rL = 1.f / L;
        float fa[16] = {};
#pragma unroll
        for (int s = 0; s < KVS; ++s) {
            const __bf16* p = yac + ((size_t)s * NROW + row0 + qq) * DI + ds * 16;
            bf16x8 v0 = *(const bf16x8*)p;
            bf16x8 v1 = *(const bf16x8*)(p + 8);
#pragma unroll
            for (int i = 0; i < 8; ++i) { fa[i] += (float)v0[i]; fa[8 + i] += (float)v1[i]; }
        }
        bf16x8 o0, o1;
#pragma unroll
        for (int i = 0; i < 8; ++i) { o0[i] = (__bf16)(fa[i] * rL); o1[i] = (__bf16)(fa[8 + i] * rL); }
        int base = qq * 128 + ds * 16;
        *(bf16x8*)(&Yt[base ^ ((qq & 7) << 3)])       = o0;
        *(bf16x8*)(&Yt[(base + 8) ^ ((qq & 7) << 3)]) = o1;
    }
    __syncthreads();

    // phase 2: W projection + bias + residual for cols [ch*128, ch*128+128)
    const int wv = tid >> 6, lane = tid & 63, l31 = lane & 31, h = lane >> 5;
    bf16x8 af[8];
#pragma unroll
    for (int kk = 0; kk < 8; ++kk)
        af[kk] = *(const bf16x8*)(&Yt[(l31 * 128 + kk * 16 + h * 8) ^ ((l31 & 7) << 3)]);

    const int col0 = ch * 128 + wv * 32;
    f32x16 acc = {};
#pragma unroll
    for (int kk = 0; kk < 8; ++kk) {
        bf16x8 bfr = *(const bf16x8*)(WwT + (size_t)(col0 + l31) * DI + kk * 16 + h * 8);
        acc = mfma(af[kk], bfr, acc);
    }

    const int col = col0 + l31;
    const float bv = bias[col];
#pragma unroll
    for (int r = 0; r < 16; ++r) {
        int row = row0 + crow(r, h);
        out[(size_t)row * CDIM + col] = acc[r] + bv + x[(size_t)row * CDIM + col];
    }
}

// ---------------------------------------------------------------------------
extern "C" void kernel_launch(void* const* d_in, const int* in_sizes, int n_in,
                              void* d_out, int out_size, void* d_ws, size_t ws_size,
                              hipStream_t stream)
{
    const float* x    = (const float*)d_in[0];
    const float* g_w  = (const float*)d_in[1];
    const float* g_b  = (const float*)d_in[2];
    const float* th_w = (const float*)d_in[3];
    const float* th_b = (const float*)d_in[4];
    const float* ph_w = (const float*)d_in[5];
    const float* ph_b = (const float*)d_in[6];
    const float* W_w  = (const float*)d_in[7];
    const float* W_b  = (const float*)d_in[8];
    float* out = (float*)d_out;

    char* ws = (char*)d_ws;
    __bf16* qws  = (__bf16*)(ws);                                 // 2 MB theta (pre-scaled)
    __bf16* kws  = (__bf16*)(ws + (2ull << 20));                  // 2 MB phi
    __bf16* vTws = (__bf16*)(ws + (4ull << 20));                  // 2 MB g^T
    __bf16* thT  = (__bf16*)(ws + (6ull << 20));                  // 64 KB
    __bf16* phT  = (__bf16*)(ws + (6ull << 20) + (64ull << 10));  // 64 KB
    __bf16* gTw  = (__bf16*)(ws + (6ull << 20) + (128ull << 10)); // 64 KB
    __bf16* WwT  = (__bf16*)(ws + (6ull << 20) + (192ull << 10)); // 64 KB
    float*  mll  = (float*)(ws + (6ull << 20) + (256ull << 10));  // 256 KB
    __bf16* yac  = (__bf16*)(ws + (7ull << 20));                  // 16 MB bf16 partials

    prep_wT<<<dim3(128, 4), 256, 0, stream>>>(th_w, ph_w, g_w, W_w,
                                              thT, phT, gTw, WwT);
    proj3<<<dim3(256, 3), 256, 0, stream>>>(x, thT, th_b, phT, ph_b,
                                            gTw, g_b, qws, kws, vTws);
    flash<<<512, 256, 0, stream>>>(qws, kws, vTws, yac, mll);
    merge_final<<<512, 256, 0, stream>>>(yac, mll, WwT, W_b, x, out);
}